// Round 10
// baseline (184.457 us; speedup 1.0000x reference)
//
#include <hip/hip_runtime.h>
#include <math.h>

#define BB 4096
#define PP 512
#define WDT 10
#define NP 4            // pairs per thread (consecutive)
#define NT 128          // threads per block

typedef float float2v __attribute__((ext_vector_type(2)));
typedef float float4v __attribute__((ext_vector_type(4)));

#define PKFMA(a, b, c) __builtin_elementwise_fma(a, b, c)
#define PKMAX(a, b)    __builtin_elementwise_max(a, b)
#define FENCE()        __builtin_amdgcn_sched_barrier(0)

__device__ __forceinline__ float2v bc2(float s) { return (float2v){s, s}; }

// tanh(x) = 1 - 2/(exp2(2*log2e*x)+1); inf-safe without clamps.
__device__ __forceinline__ float fast_tanh(float x) {
    float e = __builtin_amdgcn_exp2f(x * 2.8853900817779268f); // v_exp_f32
    return 1.0f - 2.0f * __builtin_amdgcn_rcpf(e + 1.0f);      // v_rcp_f32
}

// Weights: wave-uniform compile-time-offset loads -> SGPRs, PHASED (<=60
// floats live per phase, sched_barrier fences) so no SGPR spill (R1/R3).
// 4 CONSECUTIVE pairs per thread: per-thread input slab is contiguous and
// 16B-aligned -> float4 loads (14 vs 56 VMEM ops), and 4 independent
// dependency chains fill the trans/FMA latency (R8 lesson: idle scales with
// in-phase dependency stalls, not per-wave overhead).
__global__ __launch_bounds__(NT) void frc_2b_kernel(
    const float* __restrict__ invar,    // [B,P,5]
    const float* __restrict__ vectors,  // [B,P,9]
    const float* __restrict__ w1_0,     // [5,10]
    const float* __restrict__ b1_0,     // [10]
    const float* __restrict__ w1_1,     // [10,10]
    const float* __restrict__ b1_1,     // [10]
    const float* __restrict__ lin0_w,   // [3,10]
    const float* __restrict__ na0_b,    // [10]
    const float* __restrict__ lin1_w,   // [10,10]
    const float* __restrict__ na1_b,    // [10]
    const float* __restrict__ final_w,  // [10,1]
    float* __restrict__ out)            // [B,3]
{
    __shared__ float red[2][3];

    const int b   = blockIdx.x;
    const int tid = threadIdx.x;

    // ---- per-thread inputs: 4 consecutive pairs, vectorized float4 loads
    const float* iv0 = invar   + ((size_t)b * PP + tid * NP) * 5;  // 20 floats, 16B-aligned
    const float* vv0 = vectors + ((size_t)b * PP + tid * NP) * 9;  // 36 floats, 16B-aligned
    float in5a[NP][5];
    float v[NP][9];
    #pragma unroll
    for (int q = 0; q < 5; ++q) {
        float4v f = ((const float4v*)iv0)[q];
        #pragma unroll
        for (int r = 0; r < 4; ++r) {
            int idx = q * 4 + r;
            in5a[idx / 5][idx % 5] = f[r];
        }
    }
    #pragma unroll
    for (int q = 0; q < 9; ++q) {
        float4v f = ((const float4v*)vv0)[q];
        #pragma unroll
        for (int r = 0; r < 4; ++r) {
            int idx = q * 4 + r;
            v[idx / 9][idx % 9] = f[r];
        }
    }

    const float k3sq  = 0.33333333333333333f;   // (1/sqrt3)^2
    const float k3k10 = 0.18257418583505536f;   // 1/sqrt(30)
    const float k10   = 0.31622776601683794f;   // 1/sqrt(10)
    const float2v z2  = {0.f, 0.f};

    // ================= Phase 1: L1  y = relu(in5 @ w1_0 + b1_0)
    float2v yp[NP][5];
    #pragma unroll
    for (int jp = 0; jp < 5; ++jp) {
        float2v bb = *(const float2v*)(b1_0 + 2 * jp);
        #pragma unroll
        for (int pr = 0; pr < NP; ++pr) yp[pr][jp] = bb;
    }
    #pragma unroll
    for (int i = 0; i < 5; ++i) {
        #pragma unroll
        for (int jp = 0; jp < 5; ++jp) {
            float2v wp = *(const float2v*)(w1_0 + i * WDT + 2 * jp);
            #pragma unroll
            for (int pr = 0; pr < NP; ++pr)
                yp[pr][jp] = PKFMA(wp, bc2(in5a[pr][i]), yp[pr][jp]);
        }
    }
    #pragma unroll
    for (int pr = 0; pr < NP; ++pr)
        #pragma unroll
        for (int jp = 0; jp < 5; ++jp) yp[pr][jp] = PKMAX(yp[pr][jp], z2);
    FENCE();

    // ================= Phase 2: L2  y2 = relu(y @ w1_1 + b1_1), k-halves
    float2v y2p[NP][5];
    #pragma unroll
    for (int jp = 0; jp < 5; ++jp) {
        float2v bb = *(const float2v*)(b1_1 + 2 * jp);
        #pragma unroll
        for (int pr = 0; pr < NP; ++pr) y2p[pr][jp] = bb;
    }
    #pragma unroll
    for (int k = 0; k < 5; ++k) {
        #pragma unroll
        for (int jp = 0; jp < 5; ++jp) {
            float2v wp = *(const float2v*)(w1_1 + k * WDT + 2 * jp);
            #pragma unroll
            for (int pr = 0; pr < NP; ++pr)
                y2p[pr][jp] = PKFMA(wp, bc2(yp[pr][k >> 1][k & 1]), y2p[pr][jp]);
        }
    }
    FENCE();
    #pragma unroll
    for (int k = 5; k < WDT; ++k) {
        #pragma unroll
        for (int jp = 0; jp < 5; ++jp) {
            float2v wp = *(const float2v*)(w1_1 + k * WDT + 2 * jp);
            #pragma unroll
            for (int pr = 0; pr < NP; ++pr)
                y2p[pr][jp] = PKFMA(wp, bc2(yp[pr][k >> 1][k & 1]), y2p[pr][jp]);
        }
    }
    #pragma unroll
    for (int pr = 0; pr < NP; ++pr)
        #pragma unroll
        for (int jp = 0; jp < 5; ++jp) y2p[pr][jp] = PKMAX(y2p[pr][jp], z2);
    FENCE();

    // ================= Phase 3: lin0 + NormActivation
    float2v c0p[NP][5], c1p[NP][5], c2p[NP][5];
    #pragma unroll
    for (int pr = 0; pr < NP; ++pr)
        #pragma unroll
        for (int jp = 0; jp < 5; ++jp) { c0p[pr][jp] = z2; c1p[pr][jp] = z2; c2p[pr][jp] = z2; }
    #pragma unroll
    for (int u = 0; u < 3; ++u) {
        #pragma unroll
        for (int jp = 0; jp < 5; ++jp) {
            float2v wp = *(const float2v*)(lin0_w + u * WDT + 2 * jp);
            #pragma unroll
            for (int pr = 0; pr < NP; ++pr) {
                c0p[pr][jp] = PKFMA(wp, bc2(v[pr][u * 3 + 0]), c0p[pr][jp]);
                c1p[pr][jp] = PKFMA(wp, bc2(v[pr][u * 3 + 1]), c1p[pr][jp]);
                c2p[pr][jp] = PKFMA(wp, bc2(v[pr][u * 3 + 2]), c2p[pr][jp]);
            }
        }
    }
    // x stored with 1/sqrt(30) folded in
    float2v x0p[NP][5], x1p[NP][5], x2p[NP][5];
    #pragma unroll
    for (int jp = 0; jp < 5; ++jp) {
        float2v nab = *(const float2v*)(na0_b + 2 * jp);
        #pragma unroll
        for (int pr = 0; pr < NP; ++pr) {
            float2v n2p = PKFMA(c0p[pr][jp], c0p[pr][jp],
                          PKFMA(c1p[pr][jp], c1p[pr][jp], c2p[pr][jp] * c2p[pr][jp]));
            float2v mp  = PKMAX(n2p * bc2(k3sq), bc2(1e-12f));
            float fh[2];
            #pragma unroll
            for (int h = 0; h < 2; ++h) {
                float m     = mp[h];
                float inv_n = __builtin_amdgcn_rsqf(m);
                float n     = m * inv_n;
                float t     = fast_tanh(n + nab[h]);
                fh[h] = t * inv_n * k3k10;
            }
            float2v fp = {fh[0], fh[1]};
            x0p[pr][jp] = c0p[pr][jp] * fp;
            x1p[pr][jp] = c1p[pr][jp] * fp;
            x2p[pr][jp] = c2p[pr][jp] * fp;
        }
    }
    FENCE();

    // ================= Phase 4: lin1 (k-halves) + NormActivation + gate + final
    float2v e0p[NP][5], e1p[NP][5], e2p[NP][5];
    #pragma unroll
    for (int pr = 0; pr < NP; ++pr)
        #pragma unroll
        for (int jp = 0; jp < 5; ++jp) { e0p[pr][jp] = z2; e1p[pr][jp] = z2; e2p[pr][jp] = z2; }
    #pragma unroll
    for (int u = 0; u < 5; ++u) {
        #pragma unroll
        for (int jp = 0; jp < 5; ++jp) {
            float2v wp = *(const float2v*)(lin1_w + u * WDT + 2 * jp);
            #pragma unroll
            for (int pr = 0; pr < NP; ++pr) {
                e0p[pr][jp] = PKFMA(wp, bc2(x0p[pr][u >> 1][u & 1]), e0p[pr][jp]);
                e1p[pr][jp] = PKFMA(wp, bc2(x1p[pr][u >> 1][u & 1]), e1p[pr][jp]);
                e2p[pr][jp] = PKFMA(wp, bc2(x2p[pr][u >> 1][u & 1]), e2p[pr][jp]);
            }
        }
    }
    FENCE();
    #pragma unroll
    for (int u = 5; u < WDT; ++u) {
        #pragma unroll
        for (int jp = 0; jp < 5; ++jp) {
            float2v wp = *(const float2v*)(lin1_w + u * WDT + 2 * jp);
            #pragma unroll
            for (int pr = 0; pr < NP; ++pr) {
                e0p[pr][jp] = PKFMA(wp, bc2(x0p[pr][u >> 1][u & 1]), e0p[pr][jp]);
                e1p[pr][jp] = PKFMA(wp, bc2(x1p[pr][u >> 1][u & 1]), e1p[pr][jp]);
                e2p[pr][jp] = PKFMA(wp, bc2(x2p[pr][u >> 1][u & 1]), e2p[pr][jp]);
            }
        }
    }
    FENCE();

    float2v a0p = z2, a1p = z2, a2p = z2;
    #pragma unroll
    for (int jp = 0; jp < 5; ++jp) {
        float2v nab = *(const float2v*)(na1_b + 2 * jp);
        float2v fwp = *(const float2v*)(final_w + 2 * jp);
        #pragma unroll
        for (int pr = 0; pr < NP; ++pr) {
            // e == reference y2v (scales folded upstream)
            float2v n2p = PKFMA(e0p[pr][jp], e0p[pr][jp],
                          PKFMA(e1p[pr][jp], e1p[pr][jp], e2p[pr][jp] * e2p[pr][jp]));
            float2v mp  = PKMAX(n2p, bc2(1e-12f));
            float gh[2];
            #pragma unroll
            for (int h = 0; h < 2; ++h) {
                float m     = mp[h];
                float inv_n = __builtin_amdgcn_rsqf(m);
                float n     = m * inv_n;
                float t     = fast_tanh(n + nab[h]);
                gh[h] = y2p[pr][jp][h] * t * inv_n * fwp[h];
            }
            float2v gp = {gh[0], gh[1]};
            a0p = PKFMA(e0p[pr][jp], gp, a0p);
            a1p = PKFMA(e1p[pr][jp], gp, a1p);
            a2p = PKFMA(e2p[pr][jp], gp, a2p);
        }
    }
    // final 1/sqrt(10) pulled out of the j-sum (linear)
    float acc0 = (a0p[0] + a0p[1]) * k10;
    float acc1 = (a1p[0] + a1p[1]) * k10;
    float acc2 = (a2p[0] + a2p[1]) * k10;

    // ---- reduce 128 threads (512 pairs) -> out[b][0..2]
    #pragma unroll
    for (int off = 32; off > 0; off >>= 1) {
        acc0 += __shfl_down(acc0, off, 64);
        acc1 += __shfl_down(acc1, off, 64);
        acc2 += __shfl_down(acc2, off, 64);
    }
    const int wave = tid >> 6;
    if ((tid & 63) == 0) { red[wave][0] = acc0; red[wave][1] = acc1; red[wave][2] = acc2; }
    __syncthreads();
    if (tid == 0) {
        out[b * 3 + 0] = red[0][0] + red[1][0];
        out[b * 3 + 1] = red[0][1] + red[1][1];
        out[b * 3 + 2] = red[0][2] + red[1][2];
    }
}

extern "C" void kernel_launch(void* const* d_in, const int* in_sizes, int n_in,
                              void* d_out, int out_size, void* d_ws, size_t ws_size,
                              hipStream_t stream) {
    const float* invar   = (const float*)d_in[0];
    const float* vectors = (const float*)d_in[1];
    const float* w1_0    = (const float*)d_in[2];
    const float* b1_0    = (const float*)d_in[3];
    const float* w1_1    = (const float*)d_in[4];
    const float* b1_1    = (const float*)d_in[5];
    const float* lin0_w  = (const float*)d_in[6];
    const float* na0_b   = (const float*)d_in[7];
    const float* lin1_w  = (const float*)d_in[8];
    const float* na1_b   = (const float*)d_in[9];
    const float* final_w = (const float*)d_in[10];
    float* out = (float*)d_out;

    frc_2b_kernel<<<BB, NT, 0, stream>>>(invar, vectors, w1_0, b1_0, w1_1, b1_1,
                                         lin0_w, na0_b, lin1_w, na1_b, final_w, out);
}

// Round 11
// 180.843 us; speedup vs baseline: 1.0200x; 1.0200x over previous
//
#include <hip/hip_runtime.h>
#include <math.h>

#define BB 4096
#define PP 512
#define WDT 10
#define NT 1024         // 16 waves/block; block covers 2 batch rows

typedef float float2v __attribute__((ext_vector_type(2)));

#define PKFMA(a, b, c) __builtin_elementwise_fma(a, b, c)
#define PKMAX(a, b)    __builtin_elementwise_max(a, b)
#define FENCE()        __builtin_amdgcn_sched_barrier(0)

__device__ __forceinline__ float2v bc2(float s) { return (float2v){s, s}; }

// tanh(x) = 1 - 2/(exp2(2*log2e*x)+1); inf-safe without clamps.
__device__ __forceinline__ float fast_tanh(float x) {
    float e = __builtin_amdgcn_exp2f(x * 2.8853900817779268f); // v_exp_f32
    return 1.0f - 2.0f * __builtin_amdgcn_rcpf(e + 1.0f);      // v_rcp_f32
}

// Weights: wave-uniform compile-time-offset s_loads -> SGPRs, PHASED (<=60
// floats live per phase, sched_barrier fences) so no SGPR spill (R1/R3).
// 1 pair/thread (VGPR~36 -> 8 waves/SIMD legal), 1024-thread blocks: the
// machine holds ~2 workgroups/CU regardless of size (R5/R7/R8/R10 pattern),
// so 16-wave blocks -> up to 32 resident waves/CU and the phase-boundary /
// trans-chain stalls get hidden by TLP instead of ILP (R10 lesson).
__global__ __launch_bounds__(NT) void frc_2b_kernel(
    const float* __restrict__ invar,    // [B,P,5]
    const float* __restrict__ vectors,  // [B,P,9]
    const float* __restrict__ w1_0,     // [5,10]
    const float* __restrict__ b1_0,     // [10]
    const float* __restrict__ w1_1,     // [10,10]
    const float* __restrict__ b1_1,     // [10]
    const float* __restrict__ lin0_w,   // [3,10]
    const float* __restrict__ na0_b,    // [10]
    const float* __restrict__ lin1_w,   // [10,10]
    const float* __restrict__ na1_b,    // [10]
    const float* __restrict__ final_w,  // [10,1]
    float* __restrict__ out)            // [B,3]
{
    __shared__ float red[16][3];

    const int tid = threadIdx.x;
    const int row = tid >> 9;                    // 0/1: which batch row
    const int p   = tid & 511;                   // pair within row
    const int b   = blockIdx.x * 2 + row;

    // ---- per-lane inputs (issued first; latency hides under s_loads)
    const float* iv = invar   + ((size_t)b * PP + p) * 5;
    const float* vv = vectors + ((size_t)b * PP + p) * 9;
    float in5a[5];
    #pragma unroll
    for (int i = 0; i < 5; ++i) in5a[i] = iv[i];
    float v[9];
    #pragma unroll
    for (int i = 0; i < 9; ++i) v[i] = vv[i];

    const float k3sq  = 0.33333333333333333f;   // (1/sqrt3)^2
    const float k3k10 = 0.18257418583505536f;   // 1/sqrt(30)
    const float k10   = 0.31622776601683794f;   // 1/sqrt(10)
    const float2v z2  = {0.f, 0.f};

    // ================= Phase 1: L1  y = relu(in5 @ w1_0 + b1_0)
    float2v yp[5];
    #pragma unroll
    for (int jp = 0; jp < 5; ++jp) yp[jp] = *(const float2v*)(b1_0 + 2 * jp);
    #pragma unroll
    for (int i = 0; i < 5; ++i) {
        const float2v xb = bc2(in5a[i]);
        #pragma unroll
        for (int jp = 0; jp < 5; ++jp) {
            float2v wp = *(const float2v*)(w1_0 + i * WDT + 2 * jp);
            yp[jp] = PKFMA(wp, xb, yp[jp]);
        }
    }
    #pragma unroll
    for (int jp = 0; jp < 5; ++jp) yp[jp] = PKMAX(yp[jp], z2);
    FENCE();

    // ================= Phase 2: L2  y2 = relu(y @ w1_1 + b1_1), k-halves
    float2v y2p[5];
    #pragma unroll
    for (int jp = 0; jp < 5; ++jp) y2p[jp] = *(const float2v*)(b1_1 + 2 * jp);
    #pragma unroll
    for (int k = 0; k < 5; ++k) {
        const float2v xb = bc2(yp[k >> 1][k & 1]);
        #pragma unroll
        for (int jp = 0; jp < 5; ++jp) {
            float2v wp = *(const float2v*)(w1_1 + k * WDT + 2 * jp);
            y2p[jp] = PKFMA(wp, xb, y2p[jp]);
        }
    }
    FENCE();
    #pragma unroll
    for (int k = 5; k < WDT; ++k) {
        const float2v xb = bc2(yp[k >> 1][k & 1]);
        #pragma unroll
        for (int jp = 0; jp < 5; ++jp) {
            float2v wp = *(const float2v*)(w1_1 + k * WDT + 2 * jp);
            y2p[jp] = PKFMA(wp, xb, y2p[jp]);
        }
    }
    #pragma unroll
    for (int jp = 0; jp < 5; ++jp) y2p[jp] = PKMAX(y2p[jp], z2);
    FENCE();

    // ================= Phase 3: lin0 + NormActivation
    float2v c0p[5], c1p[5], c2p[5];
    #pragma unroll
    for (int jp = 0; jp < 5; ++jp) { c0p[jp] = z2; c1p[jp] = z2; c2p[jp] = z2; }
    #pragma unroll
    for (int u = 0; u < 3; ++u) {
        const float2v b0 = bc2(v[u * 3 + 0]);
        const float2v b1 = bc2(v[u * 3 + 1]);
        const float2v b2 = bc2(v[u * 3 + 2]);
        #pragma unroll
        for (int jp = 0; jp < 5; ++jp) {
            float2v wp = *(const float2v*)(lin0_w + u * WDT + 2 * jp);
            c0p[jp] = PKFMA(wp, b0, c0p[jp]);
            c1p[jp] = PKFMA(wp, b1, c1p[jp]);
            c2p[jp] = PKFMA(wp, b2, c2p[jp]);
        }
    }
    // x stored with 1/sqrt(30) folded in
    float2v x0p[5], x1p[5], x2p[5];
    #pragma unroll
    for (int jp = 0; jp < 5; ++jp) {
        float2v n2p = PKFMA(c0p[jp], c0p[jp], PKFMA(c1p[jp], c1p[jp], c2p[jp] * c2p[jp]));
        float2v mp  = PKMAX(n2p * bc2(k3sq), bc2(1e-12f));
        float2v nab = *(const float2v*)(na0_b + 2 * jp);
        float fh[2];
        #pragma unroll
        for (int h = 0; h < 2; ++h) {
            float m     = mp[h];
            float inv_n = __builtin_amdgcn_rsqf(m);
            float n     = m * inv_n;
            float t     = fast_tanh(n + nab[h]);
            fh[h] = t * inv_n * k3k10;
        }
        float2v fp = {fh[0], fh[1]};
        x0p[jp] = c0p[jp] * fp;
        x1p[jp] = c1p[jp] * fp;
        x2p[jp] = c2p[jp] * fp;
    }
    FENCE();

    // ================= Phase 4: lin1 (k-halves) + NormActivation + gate + final
    float2v e0p[5], e1p[5], e2p[5];
    #pragma unroll
    for (int jp = 0; jp < 5; ++jp) { e0p[jp] = z2; e1p[jp] = z2; e2p[jp] = z2; }
    #pragma unroll
    for (int u = 0; u < 5; ++u) {
        const float2v b0 = bc2(x0p[u >> 1][u & 1]);
        const float2v b1 = bc2(x1p[u >> 1][u & 1]);
        const float2v b2 = bc2(x2p[u >> 1][u & 1]);
        #pragma unroll
        for (int jp = 0; jp < 5; ++jp) {
            float2v wp = *(const float2v*)(lin1_w + u * WDT + 2 * jp);
            e0p[jp] = PKFMA(wp, b0, e0p[jp]);
            e1p[jp] = PKFMA(wp, b1, e1p[jp]);
            e2p[jp] = PKFMA(wp, b2, e2p[jp]);
        }
    }
    FENCE();
    #pragma unroll
    for (int u = 5; u < WDT; ++u) {
        const float2v b0 = bc2(x0p[u >> 1][u & 1]);
        const float2v b1 = bc2(x1p[u >> 1][u & 1]);
        const float2v b2 = bc2(x2p[u >> 1][u & 1]);
        #pragma unroll
        for (int jp = 0; jp < 5; ++jp) {
            float2v wp = *(const float2v*)(lin1_w + u * WDT + 2 * jp);
            e0p[jp] = PKFMA(wp, b0, e0p[jp]);
            e1p[jp] = PKFMA(wp, b1, e1p[jp]);
            e2p[jp] = PKFMA(wp, b2, e2p[jp]);
        }
    }
    FENCE();

    float2v a0p = z2, a1p = z2, a2p = z2;
    #pragma unroll
    for (int jp = 0; jp < 5; ++jp) {
        float2v n2p = PKFMA(e0p[jp], e0p[jp], PKFMA(e1p[jp], e1p[jp], e2p[jp] * e2p[jp]));
        float2v mp  = PKMAX(n2p, bc2(1e-12f));
        float2v nab = *(const float2v*)(na1_b + 2 * jp);
        float2v fwp = *(const float2v*)(final_w + 2 * jp);
        float gh[2];
        #pragma unroll
        for (int h = 0; h < 2; ++h) {
            float m     = mp[h];
            float inv_n = __builtin_amdgcn_rsqf(m);
            float n     = m * inv_n;
            float t     = fast_tanh(n + nab[h]);
            gh[h] = y2p[jp][h] * t * inv_n * fwp[h];
        }
        float2v gp = {gh[0], gh[1]};
        a0p = PKFMA(e0p[jp], gp, a0p);
        a1p = PKFMA(e1p[jp], gp, a1p);
        a2p = PKFMA(e2p[jp], gp, a2p);
    }
    // final 1/sqrt(10) pulled out of the j-sum (linear)
    float acc0 = (a0p[0] + a0p[1]) * k10;
    float acc1 = (a1p[0] + a1p[1]) * k10;
    float acc2 = (a2p[0] + a2p[1]) * k10;

    // ---- reduce: waves 0-7 -> row 0, waves 8-15 -> row 1
    #pragma unroll
    for (int off = 32; off > 0; off >>= 1) {
        acc0 += __shfl_down(acc0, off, 64);
        acc1 += __shfl_down(acc1, off, 64);
        acc2 += __shfl_down(acc2, off, 64);
    }
    const int wave = tid >> 6;
    if ((tid & 63) == 0) { red[wave][0] = acc0; red[wave][1] = acc1; red[wave][2] = acc2; }
    __syncthreads();
    if ((tid & 511) == 0) {                      // tid 0 -> row 0, tid 512 -> row 1
        const int base = row * 8;
        float r0 = 0.f, r1 = 0.f, r2 = 0.f;
        #pragma unroll
        for (int wv = 0; wv < 8; ++wv) {
            r0 += red[base + wv][0];
            r1 += red[base + wv][1];
            r2 += red[base + wv][2];
        }
        out[b * 3 + 0] = r0;
        out[b * 3 + 1] = r1;
        out[b * 3 + 2] = r2;
    }
}

extern "C" void kernel_launch(void* const* d_in, const int* in_sizes, int n_in,
                              void* d_out, int out_size, void* d_ws, size_t ws_size,
                              hipStream_t stream) {
    const float* invar   = (const float*)d_in[0];
    const float* vectors = (const float*)d_in[1];
    const float* w1_0    = (const float*)d_in[2];
    const float* b1_0    = (const float*)d_in[3];
    const float* w1_1    = (const float*)d_in[4];
    const float* b1_1    = (const float*)d_in[5];
    const float* lin0_w  = (const float*)d_in[6];
    const float* na0_b   = (const float*)d_in[7];
    const float* lin1_w  = (const float*)d_in[8];
    const float* na1_b   = (const float*)d_in[9];
    const float* final_w = (const float*)d_in[10];
    float* out = (float*)d_out;

    frc_2b_kernel<<<BB / 2, NT, 0, stream>>>(invar, vectors, w1_0, b1_0, w1_1, b1_1,
                                             lin0_w, na0_b, lin1_w, na1_b, final_w, out);
}